// Round 2
// baseline (213.654 us; speedup 1.0000x reference)
//
#include <hip/hip_runtime.h>
#include <math.h>

#define NT   196
#define EMB  256
#define NH   8
#define DH   32
#define HID  1024
#define EPSV 1e-5f

// ---------------- K1: LN1 + QKV (both streams) ----------------
// grid = 2*196 blocks, 256 threads. Block = one token row of one stream.
// NOTE: QKV is computed from the RAW input (reference applies _qkv to vis_emb,
// not to the LN output); NV holds LN1(x) for the residual later.
__global__ __launch_bounds__(256) void k1_ln_qkv(
    const float* __restrict__ vis, const float* __restrict__ ir,
    const float* __restrict__ ln1v_w, const float* __restrict__ ln1v_b,
    const float* __restrict__ ln1i_w, const float* __restrict__ ln1i_b,
    const float* __restrict__ Wqkv_v, const float* __restrict__ bqkv_v,
    const float* __restrict__ Wqkv_i, const float* __restrict__ bqkv_i,
    float* __restrict__ Q, float* __restrict__ Kq, float* __restrict__ Vq,
    float* __restrict__ NV)
{
    const int s = blockIdx.x / NT;
    const int n = blockIdx.x % NT;
    const int t = threadIdx.x;
    const float* x    = (s == 0) ? vis    : ir;
    const float* lw   = (s == 0) ? ln1v_w : ln1i_w;
    const float* lb   = (s == 0) ? ln1v_b : ln1i_b;
    const float* W    = (s == 0) ? Wqkv_v : Wqkv_i;
    const float* bias = (s == 0) ? bqkv_v : bqkv_i;

    __shared__ float xs[EMB];
    __shared__ float red[256];

    float xv = x[n*EMB + t];
    xs[t]  = xv;
    red[t] = xv;
    __syncthreads();
    for (int o = 128; o > 0; o >>= 1) { if (t < o) red[t] += red[t+o]; __syncthreads(); }
    float mean = red[0] * (1.0f/EMB);
    __syncthreads();
    float dev = xv - mean;
    red[t] = dev*dev;
    __syncthreads();
    for (int o = 128; o > 0; o >>= 1) { if (t < o) red[t] += red[t+o]; __syncthreads(); }
    float inv = rsqrtf(red[0] * (1.0f/EMB) + EPSV);
    NV[(s*NT + n)*EMB + t] = dev*inv*lw[t] + lb[t];

    // QKV: thread t computes output cols t, t+256, t+512
    float a0 = bias[t];
    float a1 = bias[t+256];
    float a2 = bias[t+512];
    for (int kk = 0; kk < EMB; kk++) {
        float xk = xs[kk];
        const float* Wr = W + kk*768;
        a0 = fmaf(xk, Wr[t],     a0);
        a1 = fmaf(xk, Wr[t+256], a1);
        a2 = fmaf(xk, Wr[t+512], a2);
    }
    float av[3] = {a0, a1, a2};
    #pragma unroll
    for (int u = 0; u < 3; u++) {
        int j = t + u*256;                 // col = h*96 + d*3 + which
        int h = j / 96, r = j % 96, d = r / 3, q = r % 3;
        float* dst = (q == 0) ? Q : (q == 1 ? Kq : Vq);
        dst[((s*NH + h)*NT + n)*DH + d] = av[u];
    }
}

// ---------------- K2: cross-attention ----------------
// grid = 2*8*4 = 64 blocks (stream, head, 49-row tile). 256 threads = 4 waves.
// Stream s queries attend to the OTHER stream's K/V.
__global__ __launch_bounds__(256) void k2_attn(
    const float* __restrict__ Q, const float* __restrict__ Kq,
    const float* __restrict__ Vq, float* __restrict__ AO)
{
    const int b    = blockIdx.x;
    const int s    = b >> 5;
    const int h    = (b >> 2) & 7;
    const int rt   = b & 3;
    const int t    = threadIdx.x;
    const int wv   = t >> 6;
    const int lane = t & 63;

    __shared__ float kl[NT*33];     // stride 33: kills 32-way bank conflicts
    __shared__ float vl[NT*33];
    __shared__ float pb[4][NT];     // per-wave softmax probabilities

    const float* Ks = Kq + ((1-s)*NH + h)*NT*DH;
    const float* Vs = Vq + ((1-s)*NH + h)*NT*DH;
    for (int idx = t; idx < NT*DH; idx += 256) {
        int j = idx >> 5, d = idx & 31;
        kl[j*33 + d] = Ks[idx];
        vl[j*33 + d] = Vs[idx];
    }
    __syncthreads();

    const float* Qs = Q + ((s*NH + h)*NT)*DH;
    const bool v3 = (lane + 192) < NT;           // lane < 4
    const int  j3 = v3 ? (lane + 192) : 0;       // safe in-bounds fallback

    for (int it = 0; it < 13; it++) {            // uniform trip count: barriers legal
        int lr = it*4 + wv;
        bool act = lr < 49;
        int i = rt*49 + lr;
        float inv_sum = 0.0f;
        if (act) {
            float qreg[DH];
            #pragma unroll
            for (int d = 0; d < DH; d++) qreg[d] = Qs[i*DH + d];
            float s0=0.f, s1=0.f, s2=0.f, s3=0.f;
            #pragma unroll
            for (int d = 0; d < DH; d++) {
                float qd = qreg[d];
                s0 = fmaf(qd, kl[(lane      )*33 + d], s0);
                s1 = fmaf(qd, kl[(lane +  64)*33 + d], s1);
                s2 = fmaf(qd, kl[(lane + 128)*33 + d], s2);
                s3 = fmaf(qd, kl[ j3        *33 + d], s3);
            }
            const float sc = 1.0f/16.0f;         // / emb_size**0.5 == 16
            s0 *= sc; s1 *= sc; s2 *= sc; s3 *= sc;
            float m = fmaxf(fmaxf(s0, s1), v3 ? fmaxf(s2, s3) : s2);
            #pragma unroll
            for (int mk = 32; mk >= 1; mk >>= 1) m = fmaxf(m, __shfl_xor(m, mk));
            float p0 = expf(s0 - m), p1 = expf(s1 - m), p2 = expf(s2 - m);
            float p3 = v3 ? expf(s3 - m) : 0.0f;
            float ls = p0 + p1 + p2 + p3;
            #pragma unroll
            for (int mk = 32; mk >= 1; mk >>= 1) ls += __shfl_xor(ls, mk);
            inv_sum = 1.0f / ls;
            pb[wv][lane]       = p0;
            pb[wv][lane +  64] = p1;
            pb[wv][lane + 128] = p2;
            if (v3) pb[wv][lane + 192] = p3;
        }
        __syncthreads();
        if (act) {
            int d = lane & 31, half = lane >> 5;
            float o = 0.0f;
            int jb = half * 98;
            for (int jj = 0; jj < 98; jj++) {
                int j = jb + jj;
                o = fmaf(pb[wv][j], vl[j*33 + d], o);
            }
            o += __shfl_xor(o, 32);
            if (lane < 32) AO[(s*NT + i)*EMB + h*DH + d] = o * inv_sum;
        }
        __syncthreads();
    }
}

// ---------------- K3: proj + residual(LN1) + LN2 ----------------
__global__ __launch_bounds__(256) void k3_proj_ln2(
    const float* __restrict__ AO, const float* __restrict__ NV,
    const float* __restrict__ Wp_v, const float* __restrict__ bp_v,
    const float* __restrict__ Wp_i, const float* __restrict__ bp_i,
    const float* __restrict__ ln2v_w, const float* __restrict__ ln2v_b,
    const float* __restrict__ ln2i_w, const float* __restrict__ ln2i_b,
    float* __restrict__ LV)
{
    const int s = blockIdx.x / NT;
    const int n = blockIdx.x % NT;
    const int t = threadIdx.x;
    const float* W  = (s == 0) ? Wp_v : Wp_i;
    const float* bp = (s == 0) ? bp_v : bp_i;
    const float* lw = (s == 0) ? ln2v_w : ln2i_w;
    const float* lb = (s == 0) ? ln2v_b : ln2i_b;
    __shared__ float ar[EMB];
    __shared__ float red[256];
    ar[t] = AO[(s*NT+n)*EMB + t];
    __syncthreads();
    float acc = bp[t];
    for (int kk = 0; kk < EMB; kk++)
        acc = fmaf(ar[kk], W[kk*EMB + t], acc);
    float r = NV[(s*NT+n)*EMB + t] + acc;
    red[t] = r;
    __syncthreads();
    for (int o = 128; o > 0; o >>= 1) { if (t < o) red[t] += red[t+o]; __syncthreads(); }
    float mean = red[0] * (1.0f/EMB);
    __syncthreads();
    float dev = r - mean;
    red[t] = dev*dev;
    __syncthreads();
    for (int o = 128; o > 0; o >>= 1) { if (t < o) red[t] += red[t+o]; __syncthreads(); }
    float inv = rsqrtf(red[0] * (1.0f/EMB) + EPSV);
    LV[(s*NT+n)*EMB + t] = dev*inv*lw[t] + lb[t];
}

// ---------------- K4: FFN1 + exact GELU ----------------
__global__ __launch_bounds__(256) void k4_ffn1(
    const float* __restrict__ LV,
    const float* __restrict__ W1v, const float* __restrict__ b1v,
    const float* __restrict__ W1i, const float* __restrict__ b1i,
    float* __restrict__ HH)
{
    const int s = blockIdx.x / NT;
    const int n = blockIdx.x % NT;
    const int t = threadIdx.x;
    const float* W  = (s == 0) ? W1v : W1i;
    const float* bb = (s == 0) ? b1v : b1i;
    __shared__ float xr[EMB];
    xr[t] = LV[(s*NT+n)*EMB + t];
    __syncthreads();
    float acc[4];
    #pragma unroll
    for (int u = 0; u < 4; u++) acc[u] = bb[t + u*256];
    for (int kk = 0; kk < EMB; kk++) {
        float xk = xr[kk];
        const float* Wr = W + kk*HID + t;
        #pragma unroll
        for (int u = 0; u < 4; u++) acc[u] = fmaf(xk, Wr[u*256], acc[u]);
    }
    #pragma unroll
    for (int u = 0; u < 4; u++) {
        float xg = acc[u];
        float g = 0.5f * xg * (1.0f + erff(xg * 0.7071067811865475f)); // exact GELU
        HH[(s*NT+n)*HID + t + u*256] = g;
    }
}

// ---------------- K5: FFN2 + residual + patch recon ----------------
__global__ __launch_bounds__(256) void k5_ffn2_out(
    const float* __restrict__ HH, const float* __restrict__ LV,
    const float* __restrict__ W2v, const float* __restrict__ b2v,
    const float* __restrict__ W2i, const float* __restrict__ b2i,
    float* __restrict__ out)
{
    const int s = blockIdx.x / NT;
    const int n = blockIdx.x % NT;
    const int t = threadIdx.x;
    const float* W  = (s == 0) ? W2v : W2i;
    const float* bb = (s == 0) ? b2v : b2i;
    __shared__ float hr[HID];
    #pragma unroll
    for (int u = 0; u < 4; u++) hr[t + u*256] = HH[(s*NT+n)*HID + t + u*256];
    __syncthreads();
    float acc = bb[t];
    for (int kk = 0; kk < HID; kk++)
        acc = fmaf(hr[kk], W[kk*EMB + t], acc);
    float val = acc + LV[(s*NT+n)*EMB + t];
    // recon: (n1,n2,p1,p2) -> f = p1*3136 + p2*196 + n1*14 + n2
    int n1 = n / 14, n2 = n % 14;
    int p1 = t >> 4, p2 = t & 15;
    int f = p1*3136 + p2*196 + n1*14 + n2;
    int ch = (s == 0) ? 1 : 0;      // channel 0 = ir (oi), channel 1 = vis (ov)
    out[ch*50176 + f] = val;
}

extern "C" void kernel_launch(void* const* d_in, const int* in_sizes, int n_in,
                              void* d_out, int out_size, void* d_ws, size_t ws_size,
                              hipStream_t stream)
{
    const float* vis    = (const float*)d_in[0];
    const float* ir     = (const float*)d_in[1];
    const float* ln1v_w = (const float*)d_in[2];
    const float* ln1v_b = (const float*)d_in[3];
    const float* ln1i_w = (const float*)d_in[4];
    const float* ln1i_b = (const float*)d_in[5];
    const float* ln2v_w = (const float*)d_in[6];
    const float* ln2v_b = (const float*)d_in[7];
    const float* ln2i_w = (const float*)d_in[8];
    const float* ln2i_b = (const float*)d_in[9];
    const float* Wqkv_v = (const float*)d_in[10];
    const float* bqkv_v = (const float*)d_in[11];
    const float* Wqkv_i = (const float*)d_in[12];
    const float* bqkv_i = (const float*)d_in[13];
    const float* Wp_v   = (const float*)d_in[14];
    const float* bp_v   = (const float*)d_in[15];
    const float* Wp_i   = (const float*)d_in[16];
    const float* bp_i   = (const float*)d_in[17];
    const float* W1v    = (const float*)d_in[18];
    const float* b1v    = (const float*)d_in[19];
    const float* W2v    = (const float*)d_in[20];
    const float* b2v    = (const float*)d_in[21];
    const float* W1i    = (const float*)d_in[22];
    const float* b1i    = (const float*)d_in[23];
    const float* W2i    = (const float*)d_in[24];
    const float* b2i    = (const float*)d_in[25];

    // Workspace layout (floats), with aliasing of dead buffers:
    //   [0]       Q   100352   -> later reused as LV
    //   [100352]  K   100352   -+
    //   [200704]  V   100352    |-> later reused as HH (401408)
    //   [301056]  NV  100352    |
    //   [401408]  AO  100352   -+
    float* ws = (float*)d_ws;
    float* Q  = ws;
    float* K  = ws + 100352;
    float* V  = ws + 200704;
    float* NV = ws + 301056;
    float* AO = ws + 401408;
    float* LV = ws;             // alias Q (dead after k2)
    float* HH = ws + 100352;    // alias K,V,NV,AO (dead after k3)

    k1_ln_qkv<<<2*NT, 256, 0, stream>>>(vis, ir, ln1v_w, ln1v_b, ln1i_w, ln1i_b,
                                        Wqkv_v, bqkv_v, Wqkv_i, bqkv_i, Q, K, V, NV);
    k2_attn<<<64, 256, 0, stream>>>(Q, K, V, AO);
    k3_proj_ln2<<<2*NT, 256, 0, stream>>>(AO, NV, Wp_v, bp_v, Wp_i, bp_i,
                                          ln2v_w, ln2v_b, ln2i_w, ln2i_b, LV);
    k4_ffn1<<<2*NT, 256, 0, stream>>>(LV, W1v, b1v, W1i, b1i, HH);
    k5_ffn2_out<<<2*NT, 256, 0, stream>>>(HH, LV, W2v, b2v, W2i, b2i, (float*)d_out);
}

// Round 3
// 169.954 us; speedup vs baseline: 1.2571x; 1.2571x over previous
//
#include <hip/hip_runtime.h>
#include <math.h>

#define NT   196
#define EMB  256
#define NH   8
#define DH   32
#define HID  1024
#define EPSV 1e-5f

// ============================================================================
// GEMM core pattern (k1,k3,k4,k5): block = 4 tokens x 256 cols.
// 256 threads = 64 col-quads x 4 K-splits. Inner iter: 1 float4 W load +
// 1 broadcast ds_read_b128 of transposed X + 16 fma. Partials -> LDS -> reduce.
// ============================================================================

// ---------------- K1: QKV (raw input @ Wqkv + bias, de-interleave) ----------
// grid = 2 * 49 * 3 = 294 blocks (stream, token-tile of 4, col-group of 256)
__global__ __launch_bounds__(256) void k1_qkv(
    const float* __restrict__ vis, const float* __restrict__ ir,
    const float* __restrict__ Wqkv_v, const float* __restrict__ bqkv_v,
    const float* __restrict__ Wqkv_i, const float* __restrict__ bqkv_i,
    float* __restrict__ Q, float* __restrict__ Kq, float* __restrict__ Vq)
{
    const int b = blockIdx.x;
    const int s = b / 147;
    const int rem = b % 147;
    const int mt = rem / 3;
    const int cg = rem % 3;
    const int n0 = mt * 4;
    const int t = threadIdx.x;

    const float* x    = (s == 0) ? vis    : ir;
    const float* W    = (s == 0) ? Wqkv_v : Wqkv_i;
    const float* bias = (s == 0) ? bqkv_v : bqkv_i;

    __shared__ float xsT[EMB * 4];     // transposed X tile [kk][r]
    __shared__ float pp[4 * 4 * 256];  // [ks][r][colInGroup]

    // load + transpose X tile: wave r holds token r, lane covers 4 cols
    {
        int r = t >> 6, c4 = (t & 63) * 4;
        float4 xv = *(const float4*)&x[(n0 + r) * EMB + c4];
        xsT[(c4 + 0) * 4 + r] = xv.x;
        xsT[(c4 + 1) * 4 + r] = xv.y;
        xsT[(c4 + 2) * 4 + r] = xv.z;
        xsT[(c4 + 3) * 4 + r] = xv.w;
    }
    __syncthreads();

    const int cq = t & 63, ks = t >> 6;
    const int col0 = cg * 256 + cq * 4;
    const float* Wb = W + col0;
    float4 a0 = {0,0,0,0}, a1 = a0, a2 = a0, a3 = a0;
    #pragma unroll 8
    for (int kk = ks * 64; kk < ks * 64 + 64; kk++) {
        float4 w4 = *(const float4*)&Wb[kk * 768];
        float4 xr = *(const float4*)&xsT[kk * 4];
        a0.x = fmaf(xr.x, w4.x, a0.x); a0.y = fmaf(xr.x, w4.y, a0.y);
        a0.z = fmaf(xr.x, w4.z, a0.z); a0.w = fmaf(xr.x, w4.w, a0.w);
        a1.x = fmaf(xr.y, w4.x, a1.x); a1.y = fmaf(xr.y, w4.y, a1.y);
        a1.z = fmaf(xr.y, w4.z, a1.z); a1.w = fmaf(xr.y, w4.w, a1.w);
        a2.x = fmaf(xr.z, w4.x, a2.x); a2.y = fmaf(xr.z, w4.y, a2.y);
        a2.z = fmaf(xr.z, w4.z, a2.z); a2.w = fmaf(xr.z, w4.w, a2.w);
        a3.x = fmaf(xr.w, w4.x, a3.x); a3.y = fmaf(xr.w, w4.y, a3.y);
        a3.z = fmaf(xr.w, w4.z, a3.z); a3.w = fmaf(xr.w, w4.w, a3.w);
    }
    *(float4*)&pp[(ks * 4 + 0) * 256 + cq * 4] = a0;
    *(float4*)&pp[(ks * 4 + 1) * 256 + cq * 4] = a1;
    *(float4*)&pp[(ks * 4 + 2) * 256 + cq * 4] = a2;
    *(float4*)&pp[(ks * 4 + 3) * 256 + cq * 4] = a3;
    __syncthreads();

    // reduce K-partials + bias, scatter to Q/K/V  (col = h*96 + d*3 + which)
    const int col = cg * 256 + t;
    const int h = col / 96, rr = col % 96, d = rr / 3, q = rr % 3;
    float* dst = (q == 0) ? Q : (q == 1 ? Kq : Vq);
    const float bval = bias[col];
    #pragma unroll
    for (int r = 0; r < 4; r++) {
        float v = pp[(0 * 4 + r) * 256 + t] + pp[(1 * 4 + r) * 256 + t]
                + pp[(2 * 4 + r) * 256 + t] + pp[(3 * 4 + r) * 256 + t] + bval;
        dst[((s * NH + h) * NT + n0 + r) * DH + d] = v;
    }
}

// ---------------- K2: cross-attention ----------------
// grid = 2*8*14 = 224 blocks (stream, head, 14-row tile). 256 threads = 4 waves.
__global__ __launch_bounds__(256) void k2_attn(
    const float* __restrict__ Q, const float* __restrict__ Kq,
    const float* __restrict__ Vq, float* __restrict__ AO)
{
    const int b  = blockIdx.x;
    const int s  = b / 112;
    const int rm = b % 112;
    const int h  = rm / 14;
    const int rt = rm % 14;
    const int t    = threadIdx.x;
    const int wv   = t >> 6;
    const int lane = t & 63;

    __shared__ float kl[NT * 33];   // stride 33: conflict-free lane-j access
    __shared__ float vl[NT * 33];
    __shared__ float pb[4][NT];

    const float4* Ks4 = (const float4*)(Kq + ((1 - s) * NH + h) * NT * DH);
    const float4* Vs4 = (const float4*)(Vq + ((1 - s) * NH + h) * NT * DH);
    for (int idx = t; idx < NT * 8; idx += 256) {   // 196 rows * 8 float4
        int j = idx >> 3, d4 = (idx & 7) * 4;
        float4 kv = Ks4[idx];
        kl[j * 33 + d4 + 0] = kv.x; kl[j * 33 + d4 + 1] = kv.y;
        kl[j * 33 + d4 + 2] = kv.z; kl[j * 33 + d4 + 3] = kv.w;
        float4 vv = Vs4[idx];
        vl[j * 33 + d4 + 0] = vv.x; vl[j * 33 + d4 + 1] = vv.y;
        vl[j * 33 + d4 + 2] = vv.z; vl[j * 33 + d4 + 3] = vv.w;
    }
    __syncthreads();

    const float* Qs = Q + ((s * NH + h) * NT) * DH;
    const bool v3 = (lane + 192) < NT;
    const int  j3 = v3 ? (lane + 192) : 0;

    for (int it = 0; it < 4; it++) {     // uniform trips: ceil(14/4)
        int lr = it * 4 + wv;
        bool act = lr < 14;
        int i = rt * 14 + lr;
        float inv_sum = 0.0f;
        if (act) {
            float qreg[DH];
            #pragma unroll
            for (int d = 0; d < DH; d++) qreg[d] = Qs[i * DH + d];
            float s0 = 0.f, s1 = 0.f, s2 = 0.f, s3 = 0.f;
            #pragma unroll
            for (int d = 0; d < DH; d++) {
                float qd = qreg[d];
                s0 = fmaf(qd, kl[(lane      ) * 33 + d], s0);
                s1 = fmaf(qd, kl[(lane +  64) * 33 + d], s1);
                s2 = fmaf(qd, kl[(lane + 128) * 33 + d], s2);
                s3 = fmaf(qd, kl[ j3          * 33 + d], s3);
            }
            const float sc = 1.0f / 16.0f;
            s0 *= sc; s1 *= sc; s2 *= sc; s3 *= sc;
            float m = fmaxf(fmaxf(s0, s1), v3 ? fmaxf(s2, s3) : s2);
            #pragma unroll
            for (int mk = 32; mk >= 1; mk >>= 1) m = fmaxf(m, __shfl_xor(m, mk));
            float p0 = expf(s0 - m), p1 = expf(s1 - m), p2 = expf(s2 - m);
            float p3 = v3 ? expf(s3 - m) : 0.0f;
            float ls = p0 + p1 + p2 + p3;
            #pragma unroll
            for (int mk = 32; mk >= 1; mk >>= 1) ls += __shfl_xor(ls, mk);
            inv_sum = 1.0f / ls;
            pb[wv][lane]       = p0;
            pb[wv][lane +  64] = p1;
            pb[wv][lane + 128] = p2;
            if (v3) pb[wv][lane + 192] = p3;
        }
        __syncthreads();
        if (act) {
            int d = lane & 31, half = lane >> 5;
            float o = 0.0f;
            int jb = half * 98;
            for (int jj = 0; jj < 98; jj++) {
                int j = jb + jj;
                o = fmaf(pb[wv][j], vl[j * 33 + d], o);
            }
            o += __shfl_xor(o, 32);
            if (lane < 32) AO[(s * NT + i) * EMB + h * DH + d] = o * inv_sum;
        }
        __syncthreads();
    }
}

// ---------------- K3: proj + LN1(x) residual + LN2 ----------------
// grid = 2 * 49 = 98 blocks (full 256-col width per block)
__global__ __launch_bounds__(256) void k3_proj_ln2(
    const float* __restrict__ vis, const float* __restrict__ ir,
    const float* __restrict__ AO,
    const float* __restrict__ ln1v_w, const float* __restrict__ ln1v_b,
    const float* __restrict__ ln1i_w, const float* __restrict__ ln1i_b,
    const float* __restrict__ Wp_v, const float* __restrict__ bp_v,
    const float* __restrict__ Wp_i, const float* __restrict__ bp_i,
    const float* __restrict__ ln2v_w, const float* __restrict__ ln2v_b,
    const float* __restrict__ ln2i_w, const float* __restrict__ ln2i_b,
    float* __restrict__ LV)
{
    const int b = blockIdx.x;
    const int s = b / 49;
    const int n0 = (b % 49) * 4;
    const int t = threadIdx.x;

    const float* x   = (s == 0) ? vis    : ir;
    const float* W   = (s == 0) ? Wp_v   : Wp_i;
    const float* bp  = (s == 0) ? bp_v   : bp_i;
    const float* l1w = (s == 0) ? ln1v_w : ln1i_w;
    const float* l1b = (s == 0) ? ln1v_b : ln1i_b;
    const float* l2w = (s == 0) ? ln2v_w : ln2i_w;
    const float* l2b = (s == 0) ? ln2v_b : ln2i_b;

    __shared__ float aoT[EMB * 4];
    __shared__ float pp[4 * 4 * 256];
    __shared__ float nvb[4 * 256];
    __shared__ float rbuf[4 * 256];

    const int r = t >> 6, lane = t & 63, c4 = lane * 4;

    // LN1 inline: wave r holds token r
    {
        float4 xv = *(const float4*)&x[(n0 + r) * EMB + c4];
        float sum = xv.x + xv.y + xv.z + xv.w;
        float sq  = xv.x*xv.x + xv.y*xv.y + xv.z*xv.z + xv.w*xv.w;
        #pragma unroll
        for (int mk = 32; mk >= 1; mk >>= 1) {
            sum += __shfl_xor(sum, mk);
            sq  += __shfl_xor(sq,  mk);
        }
        float mean = sum * (1.0f / EMB);
        float inv  = rsqrtf(sq * (1.0f / EMB) - mean * mean + EPSV);
        float4 wv4 = *(const float4*)&l1w[c4];
        float4 bv4 = *(const float4*)&l1b[c4];
        nvb[r * 256 + c4 + 0] = (xv.x - mean) * inv * wv4.x + bv4.x;
        nvb[r * 256 + c4 + 1] = (xv.y - mean) * inv * wv4.y + bv4.y;
        nvb[r * 256 + c4 + 2] = (xv.z - mean) * inv * wv4.z + bv4.z;
        nvb[r * 256 + c4 + 3] = (xv.w - mean) * inv * wv4.w + bv4.w;
        // AO tile transpose
        float4 av = *(const float4*)&AO[(s * NT + n0 + r) * EMB + c4];
        aoT[(c4 + 0) * 4 + r] = av.x;
        aoT[(c4 + 1) * 4 + r] = av.y;
        aoT[(c4 + 2) * 4 + r] = av.z;
        aoT[(c4 + 3) * 4 + r] = av.w;
    }
    __syncthreads();

    const int cq = t & 63, ks = t >> 6;
    const int col0 = cq * 4;
    const float* Wb = W + col0;
    float4 a0 = {0,0,0,0}, a1 = a0, a2 = a0, a3 = a0;
    #pragma unroll 8
    for (int kk = ks * 64; kk < ks * 64 + 64; kk++) {
        float4 w4 = *(const float4*)&Wb[kk * EMB];
        float4 xr = *(const float4*)&aoT[kk * 4];
        a0.x = fmaf(xr.x, w4.x, a0.x); a0.y = fmaf(xr.x, w4.y, a0.y);
        a0.z = fmaf(xr.x, w4.z, a0.z); a0.w = fmaf(xr.x, w4.w, a0.w);
        a1.x = fmaf(xr.y, w4.x, a1.x); a1.y = fmaf(xr.y, w4.y, a1.y);
        a1.z = fmaf(xr.y, w4.z, a1.z); a1.w = fmaf(xr.y, w4.w, a1.w);
        a2.x = fmaf(xr.z, w4.x, a2.x); a2.y = fmaf(xr.z, w4.y, a2.y);
        a2.z = fmaf(xr.z, w4.z, a2.z); a2.w = fmaf(xr.z, w4.w, a2.w);
        a3.x = fmaf(xr.w, w4.x, a3.x); a3.y = fmaf(xr.w, w4.y, a3.y);
        a3.z = fmaf(xr.w, w4.z, a3.z); a3.w = fmaf(xr.w, w4.w, a3.w);
    }
    *(float4*)&pp[(ks * 4 + 0) * 256 + cq * 4] = a0;
    *(float4*)&pp[(ks * 4 + 1) * 256 + cq * 4] = a1;
    *(float4*)&pp[(ks * 4 + 2) * 256 + cq * 4] = a2;
    *(float4*)&pp[(ks * 4 + 3) * 256 + cq * 4] = a3;
    __syncthreads();

    // residual add: r = LN1(x) + proj(AO)+bp
    {
        const float bval = bp[t];
        #pragma unroll
        for (int r2 = 0; r2 < 4; r2++) {
            float v = pp[(0 * 4 + r2) * 256 + t] + pp[(1 * 4 + r2) * 256 + t]
                    + pp[(2 * 4 + r2) * 256 + t] + pp[(3 * 4 + r2) * 256 + t]
                    + bval + nvb[r2 * 256 + t];
            rbuf[r2 * 256 + t] = v;
        }
    }
    __syncthreads();

    // LN2: wave r handles token r
    {
        float4 rv = *(const float4*)&rbuf[r * 256 + c4];
        float sum = rv.x + rv.y + rv.z + rv.w;
        float sq  = rv.x*rv.x + rv.y*rv.y + rv.z*rv.z + rv.w*rv.w;
        #pragma unroll
        for (int mk = 32; mk >= 1; mk >>= 1) {
            sum += __shfl_xor(sum, mk);
            sq  += __shfl_xor(sq,  mk);
        }
        float mean = sum * (1.0f / EMB);
        float inv  = rsqrtf(sq * (1.0f / EMB) - mean * mean + EPSV);
        float4 wv4 = *(const float4*)&l2w[c4];
        float4 bv4 = *(const float4*)&l2b[c4];
        float4 o;
        o.x = (rv.x - mean) * inv * wv4.x + bv4.x;
        o.y = (rv.y - mean) * inv * wv4.y + bv4.y;
        o.z = (rv.z - mean) * inv * wv4.z + bv4.z;
        o.w = (rv.w - mean) * inv * wv4.w + bv4.w;
        *(float4*)&LV[(s * NT + n0 + r) * EMB + c4] = o;
    }
}

// ---------------- K4: FFN1 + exact GELU ----------------
// grid = 2 * 49 * 4 = 392 blocks (col-groups of 256 over HID=1024)
__global__ __launch_bounds__(256) void k4_ffn1(
    const float* __restrict__ LV,
    const float* __restrict__ W1v, const float* __restrict__ b1v,
    const float* __restrict__ W1i, const float* __restrict__ b1i,
    float* __restrict__ HH)
{
    const int b = blockIdx.x;
    const int s = b / 196;
    const int rem = b % 196;
    const int mt = rem / 4;
    const int cg = rem % 4;
    const int n0 = mt * 4;
    const int t = threadIdx.x;

    const float* W  = (s == 0) ? W1v : W1i;
    const float* bb = (s == 0) ? b1v : b1i;

    __shared__ float xsT[EMB * 4];
    __shared__ float pp[4 * 4 * 256];

    {
        int r = t >> 6, c4 = (t & 63) * 4;
        float4 xv = *(const float4*)&LV[(s * NT + n0 + r) * EMB + c4];
        xsT[(c4 + 0) * 4 + r] = xv.x;
        xsT[(c4 + 1) * 4 + r] = xv.y;
        xsT[(c4 + 2) * 4 + r] = xv.z;
        xsT[(c4 + 3) * 4 + r] = xv.w;
    }
    __syncthreads();

    const int cq = t & 63, ks = t >> 6;
    const int col0 = cg * 256 + cq * 4;
    const float* Wb = W + col0;
    float4 a0 = {0,0,0,0}, a1 = a0, a2 = a0, a3 = a0;
    #pragma unroll 8
    for (int kk = ks * 64; kk < ks * 64 + 64; kk++) {
        float4 w4 = *(const float4*)&Wb[kk * HID];
        float4 xr = *(const float4*)&xsT[kk * 4];
        a0.x = fmaf(xr.x, w4.x, a0.x); a0.y = fmaf(xr.x, w4.y, a0.y);
        a0.z = fmaf(xr.x, w4.z, a0.z); a0.w = fmaf(xr.x, w4.w, a0.w);
        a1.x = fmaf(xr.y, w4.x, a1.x); a1.y = fmaf(xr.y, w4.y, a1.y);
        a1.z = fmaf(xr.y, w4.z, a1.z); a1.w = fmaf(xr.y, w4.w, a1.w);
        a2.x = fmaf(xr.z, w4.x, a2.x); a2.y = fmaf(xr.z, w4.y, a2.y);
        a2.z = fmaf(xr.z, w4.z, a2.z); a2.w = fmaf(xr.z, w4.w, a2.w);
        a3.x = fmaf(xr.w, w4.x, a3.x); a3.y = fmaf(xr.w, w4.y, a3.y);
        a3.z = fmaf(xr.w, w4.z, a3.z); a3.w = fmaf(xr.w, w4.w, a3.w);
    }
    *(float4*)&pp[(ks * 4 + 0) * 256 + cq * 4] = a0;
    *(float4*)&pp[(ks * 4 + 1) * 256 + cq * 4] = a1;
    *(float4*)&pp[(ks * 4 + 2) * 256 + cq * 4] = a2;
    *(float4*)&pp[(ks * 4 + 3) * 256 + cq * 4] = a3;
    __syncthreads();

    const int col = cg * 256 + t;
    const float bval = bb[col];
    #pragma unroll
    for (int r = 0; r < 4; r++) {
        float v = pp[(0 * 4 + r) * 256 + t] + pp[(1 * 4 + r) * 256 + t]
                + pp[(2 * 4 + r) * 256 + t] + pp[(3 * 4 + r) * 256 + t] + bval;
        float g = 0.5f * v * (1.0f + erff(v * 0.7071067811865475f));
        HH[(s * NT + n0 + r) * HID + col] = g;
    }
}

// ---------------- K5: FFN2 + residual + patch recon ----------------
// grid = 2 * 49 = 98 blocks. K=1024 split 4 ways (256 each).
__global__ __launch_bounds__(256) void k5_ffn2_out(
    const float* __restrict__ HH, const float* __restrict__ LV,
    const float* __restrict__ W2v, const float* __restrict__ b2v,
    const float* __restrict__ W2i, const float* __restrict__ b2i,
    float* __restrict__ out)
{
    const int b = blockIdx.x;
    const int s = b / 49;
    const int n0 = (b % 49) * 4;
    const int t = threadIdx.x;

    const float* W  = (s == 0) ? W2v : W2i;
    const float* bb = (s == 0) ? b2v : b2i;

    __shared__ float hhT[HID * 4];     // 16 KB
    __shared__ float pp[4 * 4 * 256];  // 16 KB

    {
        int r = t >> 6, lane = t & 63;
        #pragma unroll
        for (int rd = 0; rd < 4; rd++) {
            int c4 = rd * 256 + lane * 4;
            float4 hv = *(const float4*)&HH[(s * NT + n0 + r) * HID + c4];
            hhT[(c4 + 0) * 4 + r] = hv.x;
            hhT[(c4 + 1) * 4 + r] = hv.y;
            hhT[(c4 + 2) * 4 + r] = hv.z;
            hhT[(c4 + 3) * 4 + r] = hv.w;
        }
    }
    __syncthreads();

    const int cq = t & 63, ks = t >> 6;
    const int col0 = cq * 4;
    const float* Wb = W + col0;
    float4 a0 = {0,0,0,0}, a1 = a0, a2 = a0, a3 = a0;
    #pragma unroll 8
    for (int kk = ks * 256; kk < ks * 256 + 256; kk++) {
        float4 w4 = *(const float4*)&Wb[kk * EMB];
        float4 xr = *(const float4*)&hhT[kk * 4];
        a0.x = fmaf(xr.x, w4.x, a0.x); a0.y = fmaf(xr.x, w4.y, a0.y);
        a0.z = fmaf(xr.x, w4.z, a0.z); a0.w = fmaf(xr.x, w4.w, a0.w);
        a1.x = fmaf(xr.y, w4.x, a1.x); a1.y = fmaf(xr.y, w4.y, a1.y);
        a1.z = fmaf(xr.y, w4.z, a1.z); a1.w = fmaf(xr.y, w4.w, a1.w);
        a2.x = fmaf(xr.z, w4.x, a2.x); a2.y = fmaf(xr.z, w4.y, a2.y);
        a2.z = fmaf(xr.z, w4.z, a2.z); a2.w = fmaf(xr.z, w4.w, a2.w);
        a3.x = fmaf(xr.w, w4.x, a3.x); a3.y = fmaf(xr.w, w4.y, a3.y);
        a3.z = fmaf(xr.w, w4.z, a3.z); a3.w = fmaf(xr.w, w4.w, a3.w);
    }
    *(float4*)&pp[(ks * 4 + 0) * 256 + cq * 4] = a0;
    *(float4*)&pp[(ks * 4 + 1) * 256 + cq * 4] = a1;
    *(float4*)&pp[(ks * 4 + 2) * 256 + cq * 4] = a2;
    *(float4*)&pp[(ks * 4 + 3) * 256 + cq * 4] = a3;
    __syncthreads();

    const float bval = bb[t];
    const int p1 = t >> 4, p2 = t & 15;
    const int ch = (s == 0) ? 1 : 0;   // channel 0 = ir, 1 = vis
    #pragma unroll
    for (int r = 0; r < 4; r++) {
        int n = n0 + r;
        float v = pp[(0 * 4 + r) * 256 + t] + pp[(1 * 4 + r) * 256 + t]
                + pp[(2 * 4 + r) * 256 + t] + pp[(3 * 4 + r) * 256 + t]
                + bval + LV[(s * NT + n) * EMB + t];
        int n1 = n / 14, n2 = n % 14;
        int f = p1 * 3136 + p2 * 196 + n1 * 14 + n2;
        out[ch * 50176 + f] = v;
    }
}

extern "C" void kernel_launch(void* const* d_in, const int* in_sizes, int n_in,
                              void* d_out, int out_size, void* d_ws, size_t ws_size,
                              hipStream_t stream)
{
    const float* vis    = (const float*)d_in[0];
    const float* ir     = (const float*)d_in[1];
    const float* ln1v_w = (const float*)d_in[2];
    const float* ln1v_b = (const float*)d_in[3];
    const float* ln1i_w = (const float*)d_in[4];
    const float* ln1i_b = (const float*)d_in[5];
    const float* ln2v_w = (const float*)d_in[6];
    const float* ln2v_b = (const float*)d_in[7];
    const float* ln2i_w = (const float*)d_in[8];
    const float* ln2i_b = (const float*)d_in[9];
    const float* Wqkv_v = (const float*)d_in[10];
    const float* bqkv_v = (const float*)d_in[11];
    const float* Wqkv_i = (const float*)d_in[12];
    const float* bqkv_i = (const float*)d_in[13];
    const float* Wp_v   = (const float*)d_in[14];
    const float* bp_v   = (const float*)d_in[15];
    const float* Wp_i   = (const float*)d_in[16];
    const float* bp_i   = (const float*)d_in[17];
    const float* W1v    = (const float*)d_in[18];
    const float* b1v    = (const float*)d_in[19];
    const float* W2v    = (const float*)d_in[20];
    const float* b2v    = (const float*)d_in[21];
    const float* W1i    = (const float*)d_in[22];
    const float* b1i    = (const float*)d_in[23];
    const float* W2i    = (const float*)d_in[24];
    const float* b2i    = (const float*)d_in[25];

    float* ws = (float*)d_ws;
    float* Q  = ws;               // [2][8][196][32]
    float* K  = ws + 100352;
    float* V  = ws + 200704;
    float* AO = ws + 301056;      // [2][196][256]
    float* LV = ws + 401408;      // [2][196][256]
    float* HH = ws + 501760;      // [2][196][1024]

    k1_qkv<<<294, 256, 0, stream>>>(vis, ir, Wqkv_v, bqkv_v, Wqkv_i, bqkv_i, Q, K, V);
    k2_attn<<<224, 256, 0, stream>>>(Q, K, V, AO);
    k3_proj_ln2<<<98, 256, 0, stream>>>(vis, ir, AO, ln1v_w, ln1v_b, ln1i_w, ln1i_b,
                                        Wp_v, bp_v, Wp_i, bp_i,
                                        ln2v_w, ln2v_b, ln2i_w, ln2i_b, LV);
    k4_ffn1<<<392, 256, 0, stream>>>(LV, W1v, b1v, W1i, b1i, HH);
    k5_ffn2_out<<<98, 256, 0, stream>>>(HH, LV, W2v, b2v, W2i, b2i, (float*)d_out);
}